// Round 2
// baseline (308.213 us; speedup 1.0000x reference)
//
#include <hip/hip_runtime.h>
#include <hip/hip_bf16.h>

#define N_NODES 100000
#define N_EDGES 1000000
// P row layout per node (f16): [A' = Wc1a@z + b_c1 (128)] [B = Wc1b@z (128)]
//                              [Y = Wb@z (128)]            [Zh = f16(z) (128)]
#define PROW 512

typedef float f32x4 __attribute__((ext_vector_type(4)));
typedef _Float16 f16x8 __attribute__((ext_vector_type(8)));

__device__ inline f16x8 pack8(float4 a, float4 b) {
    f16x8 o;
    o[0] = (_Float16)a.x; o[1] = (_Float16)a.y; o[2] = (_Float16)a.z; o[3] = (_Float16)a.w;
    o[4] = (_Float16)b.x; o[5] = (_Float16)b.y; o[6] = (_Float16)b.z; o[7] = (_Float16)b.w;
    return o;
}
// 16x16x32 f16 MFMA (compiler-managed hazards/scheduling).
// A row = lane&15, B col = lane&15; A/B share the (lane>>4, reg)->k map, so any
// internally-consistent contiguous-k8 load is correct. D: col=lane&15,
// row=(lane>>4)*4+reg (m89-verified, dtype-independent).
__device__ inline void mfma16(f32x4& acc, f16x8 a, f16x8 b) {
    acc = __builtin_amdgcn_mfma_f32_16x16x32_f16(a, b, acc, 0, 0, 0);
}

// ---------------- precompute: P cols 0..383 = Z(100000x128) @ W_all^T ----------------
__global__ __launch_bounds__(256) void precomp_kernel(
    const float* __restrict__ z, const float* __restrict__ w_c1,
    const float* __restrict__ b_c1, const float* __restrict__ w_b,
    _Float16* __restrict__ P)
{
    const int lane = threadIdx.x & 63;
    const int r = lane & 15, g = lane >> 4;
    const int wid = blockIdx.x * 4 + (threadIdx.x >> 6);
    const int ct = wid % 6;          // 6 col-tiles of 64 over 384 output cols
    const int walker = wid / 6;
    const int nWalk = (gridDim.x * 4) / 6;

    // B-fragments: element j of lane = W[col][k], col = ct*64+nt*16+r
    f16x8 bw[4][4];
#pragma unroll
    for (int nt = 0; nt < 4; ++nt) {
        const int c = ct * 64 + nt * 16 + r;
        const float* wrow;
        if (c < 128)       wrow = w_c1 + (size_t)c * 256;              // Wc1a row
        else if (c < 256)  wrow = w_c1 + (size_t)(c - 128) * 256 + 128; // Wc1b row
        else               wrow = w_b + (size_t)(c - 256) * 128;       // Wb row
#pragma unroll
        for (int kk = 0; kk < 4; ++kk) {
            const int k0 = kk * 32 + g * 8;
            float4 f0 = *reinterpret_cast<const float4*>(wrow + k0);
            float4 f1 = *reinterpret_cast<const float4*>(wrow + k0 + 4);
            bw[nt][kk] = pack8(f0, f1);
        }
    }
    float bc1v[4] = {0.f, 0.f, 0.f, 0.f};
    if (ct < 2) {
#pragma unroll
        for (int nt = 0; nt < 4; ++nt) bc1v[nt] = b_c1[ct * 64 + nt * 16 + r];
    }

    for (int nb = walker; nb < N_NODES / 16; nb += nWalk) {
        const float* zp = z + (size_t)(nb * 16 + r) * 128;
        f32x4 acc[4] = {};
#pragma unroll
        for (int kk = 0; kk < 4; ++kk) {
            const int k0 = kk * 32 + g * 8;
            float4 z0 = *reinterpret_cast<const float4*>(zp + k0);
            float4 z1 = *reinterpret_cast<const float4*>(zp + k0 + 4);
            f16x8 a = pack8(z0, z1);
#pragma unroll
            for (int nt = 0; nt < 4; ++nt) mfma16(acc[nt], a, bw[nt][kk]);
        }
#pragma unroll
        for (int nt = 0; nt < 4; ++nt) {
#pragma unroll
            for (int rr = 0; rr < 4; ++rr) {
                float v = acc[nt][rr] + bc1v[nt];
                const int node = nb * 16 + g * 4 + rr;
                const int col = ct * 64 + nt * 16 + r;
                P[(size_t)node * PROW + col] = (_Float16)v;
            }
        }
    }
}

// ---------------- Zh: f16 copy of z into P cols 384..511 ----------------
__global__ __launch_bounds__(256) void zb_kernel(const float* __restrict__ z,
                                                 _Float16* __restrict__ P)
{
    const int i = blockIdx.x * 256 + threadIdx.x;
    if (i >= N_NODES * 16) return;
    const int node = i >> 4, ch = i & 15;
    const float* zp = z + (size_t)node * 128 + ch * 8;
    float4 a = *reinterpret_cast<const float4*>(zp);
    float4 b = *reinterpret_cast<const float4*>(zp + 4);
    *reinterpret_cast<f16x8*>(P + (size_t)node * PROW + 384 + ch * 8) = pack8(a, b);
}

// ---------------- main edge kernel: 16 edges per wave ----------------
__global__ __launch_bounds__(256) void edge_kernel(
    const int* __restrict__ edge, const _Float16* __restrict__ P,
    const float* __restrict__ w_h1, const float* __restrict__ b_h1,
    const float* __restrict__ w_h2, const float* __restrict__ b_h2,
    const float* __restrict__ w_c2, const float* __restrict__ b_c2,
    const float* __restrict__ b_b, const float* __restrict__ sw,
    float* __restrict__ out)
{
    __shared__ float wc2_lds[128];
    if (threadIdx.x < 128) wc2_lds[threadIdx.x] = w_c2[threadIdx.x];
    __syncthreads();

    const int lane = threadIdx.x & 63;
    const int r = lane & 15, g = lane >> 4;

    const float s0 = sw[0], s1 = sw[1], s2 = sw[2];
    const float mx = fmaxf(s0, fmaxf(s1, s2));
    const float e0 = __expf(s0 - mx), e1 = __expf(s1 - mx), e2 = __expf(s2 - mx);
    const float inv = 1.0f / (e0 + e1 + e2);
    const float W0 = e0 * inv, W1 = e1 * inv, W2 = e2 * inv;
    const float cbias = W0 * b_h2[0] + W1 * b_c2[0] + W2 * b_b[0];

    // W_h1 B-fragments held in regs
    f16x8 bw[4][4];
#pragma unroll
    for (int nt = 0; nt < 4; ++nt) {
        const float* wr = w_h1 + (size_t)(nt * 16 + r) * 128;
#pragma unroll
        for (int kk = 0; kk < 4; ++kk) {
            const int k0 = kk * 32 + g * 8;
            float4 f0 = *reinterpret_cast<const float4*>(wr + k0);
            float4 f1 = *reinterpret_cast<const float4*>(wr + k0 + 4);
            bw[nt][kk] = pack8(f0, f1);
        }
    }
    float bh1v[4], wh2v[4];
#pragma unroll
    for (int nt = 0; nt < 4; ++nt) {
        bh1v[nt] = b_h1[nt * 16 + r];
        wh2v[nt] = w_h2[nt * 16 + r];
    }

    const int gwid = (blockIdx.x * blockDim.x + threadIdx.x) >> 6;
    const int nW = (gridDim.x * blockDim.x) >> 6;
    const int e2off = g * 4 + (lane & 3);      // this lane's edge for score2/3 & output
    const int dr = ((lane >> 2) & 3) * 32;     // this lane's 32-dim slice

    for (int b = gwid; b < N_EDGES / 16; b += nW) {
        const int base = b * 16;

        // ---- score1: H(16x64) = (z_s .* z_d)(16x128) @ Wh1^T via MFMA ----
        const int2 sdA = *reinterpret_cast<const int2*>(edge + 2 * (base + r));
        const _Float16* zsp = P + (size_t)sdA.x * PROW + 384;
        const _Float16* zdp = P + (size_t)sdA.y * PROW + 384;
        f32x4 acc[4] = {};
#pragma unroll
        for (int kk = 0; kk < 4; ++kk) {
            const int k0 = kk * 32 + g * 8;
            f16x8 zs = *reinterpret_cast<const f16x8*>(zsp + k0);
            f16x8 zd = *reinterpret_cast<const f16x8*>(zdp + k0);
            f16x8 a = zs * zd;  // v_pk_mul_f16
            mfma16(acc[0], a, bw[0][kk]);
            mfma16(acc[1], a, bw[1][kk]);
            mfma16(acc[2], a, bw[2][kk]);
            mfma16(acc[3], a, bw[3][kk]);
        }
        float t4[4];
#pragma unroll
        for (int rr = 0; rr < 4; ++rr) {
            float s = 0.f;
#pragma unroll
            for (int nt = 0; nt < 4; ++nt)
                s = fmaf(fmaxf(acc[nt][rr] + bh1v[nt], 0.f), wh2v[nt], s);
            t4[rr] = s;
        }
#pragma unroll
        for (int mask = 1; mask <= 8; mask <<= 1) {
#pragma unroll
            for (int rr = 0; rr < 4; ++rr)
                t4[rr] += __shfl_xor(t4[rr], mask, 16);
        }
        const int rsel = lane & 3;
        float sc1 = t4[0];
        if (rsel == 1) sc1 = t4[1];
        if (rsel == 2) sc1 = t4[2];
        if (rsel == 3) sc1 = t4[3];   // sc1 = score1(edge base + e2off)

        // ---- score2 & score3: 4 lanes per edge, 32 dims each ----
        const int2 sd2 = *reinterpret_cast<const int2*>(edge + 2 * (base + e2off));
        const _Float16* pa = P + (size_t)sd2.x * PROW + dr;         // A'[src]
        const _Float16* pz = P + (size_t)sd2.x * PROW + 384 + dr;   // Zh[src]
        const _Float16* pb = P + (size_t)sd2.y * PROW + 128 + dr;   // B[dst]
        const _Float16* py = P + (size_t)sd2.y * PROW + 256 + dr;   // Y[dst]
        float sA = 0.f, sB = 0.f;
#pragma unroll
        for (int c = 0; c < 4; ++c) {
            const int o = c * 8;
            f16x8 va = *reinterpret_cast<const f16x8*>(pa + o);
            f16x8 vb = *reinterpret_cast<const f16x8*>(pb + o);
            f16x8 vy = *reinterpret_cast<const f16x8*>(py + o);
            f16x8 vz = *reinterpret_cast<const f16x8*>(pz + o);
            const float* wp = wc2_lds + dr + o;
#pragma unroll
            for (int j = 0; j < 8; ++j) {
                float fa = fmaxf((float)va[j] + (float)vb[j], 0.f);
                sA = fmaf(fa, wp[j], sA);
                sB = fmaf((float)vz[j], (float)vy[j], sB);
            }
        }
        sA += __shfl_xor(sA, 4, 16);
        sA += __shfl_xor(sA, 8, 16);
        sB += __shfl_xor(sB, 4, 16);
        sB += __shfl_xor(sB, 8, 16);

        const float res = fmaf(W0, sc1, fmaf(W1, sA, fmaf(W2, sB, cbias)));
        if ((lane & 12) == 0) out[base + e2off] = res;
    }
}

// ---------------- fallback: fused wave-per-edge, no workspace ----------------
__global__ __launch_bounds__(256) void fused_fallback(
    const float* __restrict__ z, const int* __restrict__ edge,
    const float* __restrict__ w_h1, const float* __restrict__ b_h1,
    const float* __restrict__ w_h2, const float* __restrict__ b_h2,
    const float* __restrict__ w_c1, const float* __restrict__ b_c1,
    const float* __restrict__ w_c2, const float* __restrict__ b_c2,
    const float* __restrict__ w_b, const float* __restrict__ b_b,
    const float* __restrict__ sw, float* __restrict__ out)
{
    __shared__ float zbuf[4][256];
    const int lane = threadIdx.x & 63;
    const int w = threadIdx.x >> 6;
    const int gw = blockIdx.x * 4 + w;
    const int nw = gridDim.x * 4;

    const float s0 = sw[0], s1 = sw[1], s2 = sw[2];
    const float mx = fmaxf(s0, fmaxf(s1, s2));
    const float e0 = __expf(s0 - mx), e1 = __expf(s1 - mx), e2 = __expf(s2 - mx);
    const float inv = 1.0f / (e0 + e1 + e2);
    const float W0 = e0 * inv, W1 = e1 * inv, W2 = e2 * inv;
    const float cbias = W0 * b_h2[0] + W1 * b_c2[0] + W2 * b_b[0];

    for (int e = gw; e < N_EDGES; e += nw) {
        const int src = edge[2 * e], dst = edge[2 * e + 1];
        const float zs0 = z[(size_t)src * 128 + lane];
        const float zs1 = z[(size_t)src * 128 + 64 + lane];
        const float zd0 = z[(size_t)dst * 128 + lane];
        const float zd1 = z[(size_t)dst * 128 + 64 + lane];
        zbuf[w][lane] = zs0; zbuf[w][64 + lane] = zs1;
        zbuf[w][128 + lane] = zd0; zbuf[w][192 + lane] = zd1;
        asm volatile("s_waitcnt lgkmcnt(0)" ::: "memory");

        // score1: h[lane]
        float h = 0.f;
        const float* whr = w_h1 + (size_t)lane * 128;
        for (int d = 0; d < 128; ++d)
            h = fmaf(zbuf[w][d] * zbuf[w][128 + d], whr[d], h);
        float sc1 = fmaxf(h + b_h1[lane], 0.f) * w_h2[lane];

        // score2: c[lane], c[lane+64]
        float c0 = 0.f, c1 = 0.f;
        const float* w0r = w_c1 + (size_t)lane * 256;
        const float* w1r = w_c1 + (size_t)(lane + 64) * 256;
        for (int d = 0; d < 256; ++d) {
            const float cat = zbuf[w][d];
            c0 = fmaf(cat, w0r[d], c0);
            c1 = fmaf(cat, w1r[d], c1);
        }
        float sc2 = fmaxf(c0 + b_c1[lane], 0.f) * w_c2[lane]
                  + fmaxf(c1 + b_c1[lane + 64], 0.f) * w_c2[lane + 64];

        // score3: d = lane, lane+64
        float t0 = 0.f, t1 = 0.f;
        const float* wb0 = w_b + (size_t)lane * 128;
        const float* wb1 = w_b + (size_t)(lane + 64) * 128;
        for (int f = 0; f < 128; ++f) {
            const float zdf = zbuf[w][128 + f];
            t0 = fmaf(wb0[f], zdf, t0);
            t1 = fmaf(wb1[f], zdf, t1);
        }
        float sc3 = zs0 * t0 + zs1 * t1;

        float v = fmaf(W0, sc1, fmaf(W1, sc2, W2 * sc3));
#pragma unroll
        for (int m = 1; m < 64; m <<= 1) v += __shfl_xor(v, m, 64);
        if (lane == 0) out[e] = v + cbias;
    }
}

extern "C" void kernel_launch(void* const* d_in, const int* in_sizes, int n_in,
                              void* d_out, int out_size, void* d_ws, size_t ws_size,
                              hipStream_t stream)
{
    const float* z    = (const float*)d_in[0];
    const int*   edge = (const int*)d_in[1];
    const float* w_h1 = (const float*)d_in[2];
    const float* b_h1 = (const float*)d_in[3];
    const float* w_h2 = (const float*)d_in[4];
    const float* b_h2 = (const float*)d_in[5];
    const float* w_c1 = (const float*)d_in[6];
    const float* b_c1 = (const float*)d_in[7];
    const float* w_c2 = (const float*)d_in[8];
    const float* b_c2 = (const float*)d_in[9];
    const float* w_b  = (const float*)d_in[10];
    const float* b_b  = (const float*)d_in[11];
    const float* sw   = (const float*)d_in[12];
    float* outp = (float*)d_out;

    const size_t needP = (size_t)N_NODES * PROW * sizeof(_Float16);  // 102.4 MB
    if (ws_size >= needP) {
        _Float16* P = (_Float16*)d_ws;
        hipLaunchKernelGGL(precomp_kernel, dim3(768), dim3(256), 0, stream,
                           z, w_c1, b_c1, w_b, P);
        hipLaunchKernelGGL(zb_kernel, dim3((N_NODES * 16 + 255) / 256), dim3(256), 0, stream,
                           z, P);
        hipLaunchKernelGGL(edge_kernel, dim3(2048), dim3(256), 0, stream,
                           edge, P, w_h1, b_h1, w_h2, b_h2, w_c2, b_c2, b_b, sw, outp);
    } else {
        hipLaunchKernelGGL(fused_fallback, dim3(4096), dim3(256), 0, stream,
                           z, edge, w_h1, b_h1, w_h2, b_h2, w_c1, b_c1,
                           w_c2, b_c2, w_b, b_b, sw, outp);
    }
}

// Round 3
// 277.182 us; speedup vs baseline: 1.1120x; 1.1120x over previous
//
#include <hip/hip_runtime.h>
#include <hip/hip_bf16.h>

#define N_NODES 100000
#define N_EDGES 1000000
// P row layout per node (f16): [A' = Wc1a@z + b_c1 (128)] [B = Wc1b@z (128)]
//                              [Y = Wb@z (128)]            [Zh = f16(z) (128)]
#define PROW 512

typedef float f32x4 __attribute__((ext_vector_type(4)));
typedef _Float16 f16x8 __attribute__((ext_vector_type(8)));
typedef _Float16 f16x2 __attribute__((ext_vector_type(2)));

__device__ inline f16x8 pack8(float4 a, float4 b) {
    f16x8 o;
    o[0] = (_Float16)a.x; o[1] = (_Float16)a.y; o[2] = (_Float16)a.z; o[3] = (_Float16)a.w;
    o[4] = (_Float16)b.x; o[5] = (_Float16)b.y; o[6] = (_Float16)b.z; o[7] = (_Float16)b.w;
    return o;
}
__device__ inline void mfma16(f32x4& acc, f16x8 a, f16x8 b) {
    acc = __builtin_amdgcn_mfma_f32_16x16x32_f16(a, b, acc, 0, 0, 0);
}
__device__ inline float fdot2(f16x8 a, f16x8 b, int j2, float c) {
    f16x2 pa = { a[2 * j2], a[2 * j2 + 1] };
    f16x2 pb = { b[2 * j2], b[2 * j2 + 1] };
    return __builtin_amdgcn_fdot2(pa, pb, c, false);
}

// ---------------- precompute: P cols 0..383 = Z @ W_all^T ; cols 384..511 = f16(z) ----
__global__ __launch_bounds__(256) void precomp_kernel(
    const float* __restrict__ z, const float* __restrict__ w_c1,
    const float* __restrict__ b_c1, const float* __restrict__ w_b,
    _Float16* __restrict__ P)
{
    const int lane = threadIdx.x & 63;
    const int r = lane & 15, g = lane >> 4;
    const int wid = blockIdx.x * 4 + (threadIdx.x >> 6);
    const int ct = wid & 7;          // 8 col-tiles of 64 over 512 P columns
    const int walker = wid >> 3;
    const int nWalk = (gridDim.x * 4) >> 3;

    if (ct >= 6) {
        // copy tiles: P cols 384+(ct-6)*64 .. +64  = f16(z cols (ct-6)*64 ..)
        const int c0 = (ct - 6) * 64 + g * 16;
        for (int nb = walker; nb < N_NODES / 16; nb += nWalk) {
            const int node = nb * 16 + r;
            const float* zp = z + (size_t)node * 128 + c0;
            float4 f0 = *reinterpret_cast<const float4*>(zp);
            float4 f1 = *reinterpret_cast<const float4*>(zp + 4);
            float4 f2 = *reinterpret_cast<const float4*>(zp + 8);
            float4 f3 = *reinterpret_cast<const float4*>(zp + 12);
            _Float16* op = P + (size_t)node * PROW + 384 + c0;
            *reinterpret_cast<f16x8*>(op) = pack8(f0, f1);
            *reinterpret_cast<f16x8*>(op + 8) = pack8(f2, f3);
        }
        return;
    }

    // B-fragments: element j of lane = W[col][k], col = ct*64+nt*16+r
    f16x8 bw[4][4];
#pragma unroll
    for (int nt = 0; nt < 4; ++nt) {
        const int c = ct * 64 + nt * 16 + r;
        const float* wrow;
        if (c < 128)       wrow = w_c1 + (size_t)c * 256;               // Wc1a row
        else if (c < 256)  wrow = w_c1 + (size_t)(c - 128) * 256 + 128; // Wc1b row
        else               wrow = w_b + (size_t)(c - 256) * 128;        // Wb row
#pragma unroll
        for (int kk = 0; kk < 4; ++kk) {
            const int k0 = kk * 32 + g * 8;
            float4 f0 = *reinterpret_cast<const float4*>(wrow + k0);
            float4 f1 = *reinterpret_cast<const float4*>(wrow + k0 + 4);
            bw[nt][kk] = pack8(f0, f1);
        }
    }
    float bc1v[4] = {0.f, 0.f, 0.f, 0.f};
    if (ct < 2) {
#pragma unroll
        for (int nt = 0; nt < 4; ++nt) bc1v[nt] = b_c1[ct * 64 + nt * 16 + r];
    }

    for (int nb = walker; nb < N_NODES / 16; nb += nWalk) {
        const float* zp = z + (size_t)(nb * 16 + r) * 128;
        f32x4 acc[4] = {};
#pragma unroll
        for (int kk = 0; kk < 4; ++kk) {
            const int k0 = kk * 32 + g * 8;
            float4 z0 = *reinterpret_cast<const float4*>(zp + k0);
            float4 z1 = *reinterpret_cast<const float4*>(zp + k0 + 4);
            f16x8 a = pack8(z0, z1);
#pragma unroll
            for (int nt = 0; nt < 4; ++nt) mfma16(acc[nt], a, bw[nt][kk]);
        }
#pragma unroll
        for (int nt = 0; nt < 4; ++nt) {
#pragma unroll
            for (int rr = 0; rr < 4; ++rr) {
                float v = acc[nt][rr] + bc1v[nt];
                const int node = nb * 16 + g * 4 + rr;
                const int col = ct * 64 + nt * 16 + r;
                P[(size_t)node * PROW + col] = (_Float16)v;
            }
        }
    }
}

// ---------------- main edge kernel: 16 edges/wave, unified lane layout ----------------
// lane = g*16 + r : edge = base + r, k-slice = {kk*32 + g*8 .. +8} for kk=0..3
__global__ __launch_bounds__(256) void edge_kernel(
    const int* __restrict__ edge, const _Float16* __restrict__ P,
    const float* __restrict__ w_h1, const float* __restrict__ b_h1,
    const float* __restrict__ w_h2, const float* __restrict__ b_h2,
    const float* __restrict__ w_c2, const float* __restrict__ b_c2,
    const float* __restrict__ b_b, const float* __restrict__ sw,
    float* __restrict__ out)
{
    // W_h1 MFMA B-fragments in LDS: entry idx = (nt*4+kk)*64 + g*16 + r, 16B each
    __shared__ f16x8 bwlds[1024];   // 16 KB

    const int tid = threadIdx.x;
    for (int e = tid; e < 1024; e += 256) {
        const int r_ = e & 15, g_ = (e >> 4) & 3, kkf = (e >> 6) & 3, ntf = e >> 8;
        const float* wr = w_h1 + (size_t)(ntf * 16 + r_) * 128 + kkf * 32 + g_ * 8;
        float4 f0 = *reinterpret_cast<const float4*>(wr);
        float4 f1 = *reinterpret_cast<const float4*>(wr + 4);
        bwlds[e] = pack8(f0, f1);
    }
    __syncthreads();

    const int lane = threadIdx.x & 63;
    const int r = lane & 15, g = lane >> 4;

    const float s0 = sw[0], s1 = sw[1], s2 = sw[2];
    const float mx = fmaxf(s0, fmaxf(s1, s2));
    const float e0 = __expf(s0 - mx), e1 = __expf(s1 - mx), e2 = __expf(s2 - mx);
    const float inv = 1.0f / (e0 + e1 + e2);
    const float W0 = e0 * inv, W1 = e1 * inv, W2 = e2 * inv;
    const float cbias = W0 * b_h2[0] + W1 * b_c2[0] + W2 * b_b[0];

    // per-lane constants: bias/out-weight for score1 (W0 folded), wc2 slices (W1 folded)
    float bh1v[4], wh2v[4];
#pragma unroll
    for (int nt = 0; nt < 4; ++nt) {
        bh1v[nt] = b_h1[nt * 16 + r];
        wh2v[nt] = w_h2[nt * 16 + r] * W0;
    }
    f16x8 wc2r[4];
#pragma unroll
    for (int kk = 0; kk < 4; ++kk) {
        const int k0 = kk * 32 + g * 8;
        float4 f0 = *reinterpret_cast<const float4*>(w_c2 + k0);
        float4 f1 = *reinterpret_cast<const float4*>(w_c2 + k0 + 4);
        f0.x *= W1; f0.y *= W1; f0.z *= W1; f0.w *= W1;
        f1.x *= W1; f1.y *= W1; f1.z *= W1; f1.w *= W1;
        wc2r[kk] = pack8(f0, f1);
    }
    const f16x8* myb = bwlds + g * 16 + r;   // + (nt*4+kk)*64

    const int gwid = (blockIdx.x * blockDim.x + threadIdx.x) >> 6;
    const int nW = (gridDim.x * blockDim.x) >> 6;
    const int2* edge2 = reinterpret_cast<const int2*>(edge);
    const int rsel = r & 3;
    const int srcl = ((r >> 2) << 4) | r;    // shfl source lane for sc1

    for (int b = gwid; b < N_EDGES / 16; b += nW) {
        const int base = b * 16;

        const int2 sd = edge2[base + r];
        const _Float16* ps = P + (size_t)sd.x * PROW;
        const _Float16* pd = P + (size_t)sd.y * PROW;

        // ---- issue all 20 gathers up front (2 bases, static offsets) ----
        f16x8 av[4], bv[4], yv[4], zs[4], zd[4];
#pragma unroll
        for (int kk = 0; kk < 4; ++kk) {
            const int off = kk * 32 + g * 8;
            av[kk] = *reinterpret_cast<const f16x8*>(ps + off);         // A'[src]
            bv[kk] = *reinterpret_cast<const f16x8*>(pd + 128 + off);   // B[dst]
            yv[kk] = *reinterpret_cast<const f16x8*>(pd + 256 + off);   // Y[dst]
            zs[kk] = *reinterpret_cast<const f16x8*>(ps + 384 + off);   // Zh[src]
            zd[kk] = *reinterpret_cast<const f16x8*>(pd + 384 + off);   // Zh[dst]
        }

        // ---- score1: H(16x64) = (zs .* zd) @ Wh1^T via MFMA ----
        f32x4 acc[4] = {};
#pragma unroll
        for (int kk = 0; kk < 4; ++kk) {
            f16x8 a = zs[kk] * zd[kk];
            mfma16(acc[0], a, myb[(0 * 4 + kk) * 64]);
            mfma16(acc[1], a, myb[(1 * 4 + kk) * 64]);
            mfma16(acc[2], a, myb[(2 * 4 + kk) * 64]);
            mfma16(acc[3], a, myb[(3 * 4 + kk) * 64]);
        }
        // lane (r,g) holds H[edge g*4+rr][nt*16+r]; fold relu+wh2, reduce over r-lanes
        float t4[4];
#pragma unroll
        for (int rr = 0; rr < 4; ++rr) {
            float s = 0.f;
#pragma unroll
            for (int nt = 0; nt < 4; ++nt)
                s = fmaf(fmaxf(acc[nt][rr] + bh1v[nt], 0.f), wh2v[nt], s);
            t4[rr] = s;
        }
#pragma unroll
        for (int mask = 1; mask <= 8; mask <<= 1) {
#pragma unroll
            for (int rr = 0; rr < 4; ++rr)
                t4[rr] += __shfl_xor(t4[rr], mask, 16);
        }
        float u = t4[0];
        if (rsel == 1) u = t4[1];
        if (rsel == 2) u = t4[2];
        if (rsel == 3) u = t4[3];
        const float sc1w = __shfl(u, srcl, 64);   // = W0-folded? no: fold below

        // ---- score2 & score3 on the same lane layout (edge r, slice g) ----
        float sA = 0.f, sB = 0.f;
#pragma unroll
        for (int kk = 0; kk < 4; ++kk) {
            f16x8 s = av[kk] + bv[kk];                       // v_pk_add_f16
            s = __builtin_elementwise_max(s, (f16x8)(_Float16)0.f);  // relu
#pragma unroll
            for (int j2 = 0; j2 < 4; ++j2) {
                sA = fdot2(s, wc2r[kk], j2, sA);             // W1 pre-folded
                sB = fdot2(zs[kk], yv[kk], j2, sB);
            }
        }
        sA += __shfl_xor(sA, 16, 64);
        sA += __shfl_xor(sA, 32, 64);
        sB += __shfl_xor(sB, 16, 64);
        sB += __shfl_xor(sB, 32, 64);

        const float res = sc1w + sA + fmaf(W2, sB, cbias);
        if (lane < 16) out[base + lane] = res;
    }
}

// ---------------- fallback: fused wave-per-edge, no workspace ----------------
__global__ __launch_bounds__(256) void fused_fallback(
    const float* __restrict__ z, const int* __restrict__ edge,
    const float* __restrict__ w_h1, const float* __restrict__ b_h1,
    const float* __restrict__ w_h2, const float* __restrict__ b_h2,
    const float* __restrict__ w_c1, const float* __restrict__ b_c1,
    const float* __restrict__ w_c2, const float* __restrict__ b_c2,
    const float* __restrict__ w_b, const float* __restrict__ b_b,
    const float* __restrict__ sw, float* __restrict__ out)
{
    __shared__ float zbuf[4][256];
    const int lane = threadIdx.x & 63;
    const int w = threadIdx.x >> 6;
    const int gw = blockIdx.x * 4 + w;
    const int nw = gridDim.x * 4;

    const float s0 = sw[0], s1 = sw[1], s2 = sw[2];
    const float mx = fmaxf(s0, fmaxf(s1, s2));
    const float e0 = __expf(s0 - mx), e1 = __expf(s1 - mx), e2 = __expf(s2 - mx);
    const float inv = 1.0f / (e0 + e1 + e2);
    const float W0 = e0 * inv, W1 = e1 * inv, W2 = e2 * inv;
    const float cbias = W0 * b_h2[0] + W1 * b_c2[0] + W2 * b_b[0];

    for (int e = gw; e < N_EDGES; e += nw) {
        const int src = edge[2 * e], dst = edge[2 * e + 1];
        const float zs0 = z[(size_t)src * 128 + lane];
        const float zs1 = z[(size_t)src * 128 + 64 + lane];
        const float zd0 = z[(size_t)dst * 128 + lane];
        const float zd1 = z[(size_t)dst * 128 + 64 + lane];
        zbuf[w][lane] = zs0; zbuf[w][64 + lane] = zs1;
        zbuf[w][128 + lane] = zd0; zbuf[w][192 + lane] = zd1;
        asm volatile("s_waitcnt lgkmcnt(0)" ::: "memory");

        float h = 0.f;
        const float* whr = w_h1 + (size_t)lane * 128;
        for (int d = 0; d < 128; ++d)
            h = fmaf(zbuf[w][d] * zbuf[w][128 + d], whr[d], h);
        float sc1 = fmaxf(h + b_h1[lane], 0.f) * w_h2[lane];

        float c0 = 0.f, c1 = 0.f;
        const float* w0r = w_c1 + (size_t)lane * 256;
        const float* w1r = w_c1 + (size_t)(lane + 64) * 256;
        for (int d = 0; d < 256; ++d) {
            const float cat = zbuf[w][d];
            c0 = fmaf(cat, w0r[d], c0);
            c1 = fmaf(cat, w1r[d], c1);
        }
        float sc2 = fmaxf(c0 + b_c1[lane], 0.f) * w_c2[lane]
                  + fmaxf(c1 + b_c1[lane + 64], 0.f) * w_c2[lane + 64];

        float t0 = 0.f, t1 = 0.f;
        const float* wb0 = w_b + (size_t)lane * 128;
        const float* wb1 = w_b + (size_t)(lane + 64) * 128;
        for (int f = 0; f < 128; ++f) {
            const float zdf = zbuf[w][128 + f];
            t0 = fmaf(wb0[f], zdf, t0);
            t1 = fmaf(wb1[f], zdf, t1);
        }
        float sc3 = zs0 * t0 + zs1 * t1;

        float v = fmaf(W0, sc1, fmaf(W1, sc2, W2 * sc3));
#pragma unroll
        for (int m = 1; m < 64; m <<= 1) v += __shfl_xor(v, m, 64);
        if (lane == 0) out[e] = v + cbias;
    }
}

extern "C" void kernel_launch(void* const* d_in, const int* in_sizes, int n_in,
                              void* d_out, int out_size, void* d_ws, size_t ws_size,
                              hipStream_t stream)
{
    const float* z    = (const float*)d_in[0];
    const int*   edge = (const int*)d_in[1];
    const float* w_h1 = (const float*)d_in[2];
    const float* b_h1 = (const float*)d_in[3];
    const float* w_h2 = (const float*)d_in[4];
    const float* b_h2 = (const float*)d_in[5];
    const float* w_c1 = (const float*)d_in[6];
    const float* b_c1 = (const float*)d_in[7];
    const float* w_c2 = (const float*)d_in[8];
    const float* b_c2 = (const float*)d_in[9];
    const float* w_b  = (const float*)d_in[10];
    const float* b_b  = (const float*)d_in[11];
    const float* sw   = (const float*)d_in[12];
    float* outp = (float*)d_out;

    const size_t needP = (size_t)N_NODES * PROW * sizeof(_Float16);  // 102.4 MB
    if (ws_size >= needP) {
        _Float16* P = (_Float16*)d_ws;
        hipLaunchKernelGGL(precomp_kernel, dim3(1024), dim3(256), 0, stream,
                           z, w_c1, b_c1, w_b, P);
        hipLaunchKernelGGL(edge_kernel, dim3(2048), dim3(256), 0, stream,
                           edge, P, w_h1, b_h1, w_h2, b_h2, w_c2, b_c2, b_b, sw, outp);
    } else {
        hipLaunchKernelGGL(fused_fallback, dim3(4096), dim3(256), 0, stream,
                           z, edge, w_h1, b_h1, w_h2, b_h2, w_c1, b_c1,
                           w_c2, b_c2, w_b, b_b, sw, outp);
    }
}

// Round 4
// 269.771 us; speedup vs baseline: 1.1425x; 1.0275x over previous
//
#include <hip/hip_runtime.h>
#include <hip/hip_bf16.h>

#define N_NODES 100000
#define N_EDGES 1000000
// P row layout per node (f16): [A' = Wc1a@z + b_c1 (128)] [B = Wc1b@z (128)]
//                              [Y = Wb@z (128)]            [Zh = f16(z) (128)]
#define PROW 512

typedef float f32x4 __attribute__((ext_vector_type(4)));
typedef _Float16 f16x8 __attribute__((ext_vector_type(8)));
typedef _Float16 f16x2 __attribute__((ext_vector_type(2)));

__device__ inline f16x8 pack8(float4 a, float4 b) {
    f16x8 o;
    o[0] = (_Float16)a.x; o[1] = (_Float16)a.y; o[2] = (_Float16)a.z; o[3] = (_Float16)a.w;
    o[4] = (_Float16)b.x; o[5] = (_Float16)b.y; o[6] = (_Float16)b.z; o[7] = (_Float16)b.w;
    return o;
}
__device__ inline void mfma16(f32x4& acc, f16x8 a, f16x8 b) {
    acc = __builtin_amdgcn_mfma_f32_16x16x32_f16(a, b, acc, 0, 0, 0);
}
__device__ inline float fdot2(f16x8 a, f16x8 b, int j2, float c) {
    f16x2 pa = { a[2 * j2], a[2 * j2 + 1] };
    f16x2 pb = { b[2 * j2], b[2 * j2 + 1] };
    return __builtin_amdgcn_fdot2(pa, pb, c, false);
}

// ---- precompute: P cols 0..383 = Z @ W_all^T ; Zh (cols 384..511) fused into ct==0 ----
__global__ __launch_bounds__(256) void precomp_kernel(
    const float* __restrict__ z, const float* __restrict__ w_c1,
    const float* __restrict__ b_c1, const float* __restrict__ w_b,
    _Float16* __restrict__ P)
{
    const int lane = threadIdx.x & 63;
    const int r = lane & 15, g = lane >> 4;
    const int wid = blockIdx.x * 4 + (threadIdx.x >> 6);
    const int ct = wid % 6;          // 6 GEMM col-tiles of 64 over 384 P columns
    const int walker = wid / 6;
    const int nWalk = (gridDim.x * 4) / 6;
    if (walker >= nWalk) return;     // avoid duplicate stragglers

    // B-fragments: element j of lane = W[col][k], col = ct*64+nt*16+r
    f16x8 bw[4][4];
#pragma unroll
    for (int nt = 0; nt < 4; ++nt) {
        const int c = ct * 64 + nt * 16 + r;
        const float* wrow;
        if (c < 128)       wrow = w_c1 + (size_t)c * 256;               // Wc1a row
        else if (c < 256)  wrow = w_c1 + (size_t)(c - 128) * 256 + 128; // Wc1b row
        else               wrow = w_b + (size_t)(c - 256) * 128;        // Wb row
#pragma unroll
        for (int kk = 0; kk < 4; ++kk) {
            const int k0 = kk * 32 + g * 8;
            float4 f0 = *reinterpret_cast<const float4*>(wrow + k0);
            float4 f1 = *reinterpret_cast<const float4*>(wrow + k0 + 4);
            bw[nt][kk] = pack8(f0, f1);
        }
    }
    float bc1v[4] = {0.f, 0.f, 0.f, 0.f};
    if (ct < 2) {
#pragma unroll
        for (int nt = 0; nt < 4; ++nt) bc1v[nt] = b_c1[ct * 64 + nt * 16 + r];
    }

    for (int nb = walker; nb < N_NODES / 16; nb += nWalk) {
        const int node_r = nb * 16 + r;
        const float* zp = z + (size_t)node_r * 128;
        f32x4 acc[4] = {};
#pragma unroll
        for (int kk = 0; kk < 4; ++kk) {
            const int k0 = kk * 32 + g * 8;
            float4 z0 = *reinterpret_cast<const float4*>(zp + k0);
            float4 z1 = *reinterpret_cast<const float4*>(zp + k0 + 4);
            f16x8 a = pack8(z0, z1);
            if (ct == 0)   // fused Zh store: exactly f16(z[node_r][k0..k0+8])
                *reinterpret_cast<f16x8*>(P + (size_t)node_r * PROW + 384 + k0) = a;
#pragma unroll
            for (int nt = 0; nt < 4; ++nt) mfma16(acc[nt], a, bw[nt][kk]);
        }
#pragma unroll
        for (int nt = 0; nt < 4; ++nt) {
#pragma unroll
            for (int rr = 0; rr < 4; ++rr) {
                float v = acc[nt][rr] + bc1v[nt];
                const int node = nb * 16 + g * 4 + rr;
                const int col = ct * 64 + nt * 16 + r;
                P[(size_t)node * PROW + col] = (_Float16)v;
            }
        }
    }
}

// ---------------- main edge kernel: 16 edges/wave, unified lane layout ----------------
// lane = g*16 + r : edge = base + r, k-slice = {kk*32 + g*8 .. +8} for kk=0..3
__global__ __launch_bounds__(256) void edge_kernel(
    const int* __restrict__ edge, const _Float16* __restrict__ P,
    const float* __restrict__ w_h1, const float* __restrict__ b_h1,
    const float* __restrict__ w_h2, const float* __restrict__ b_h2,
    const float* __restrict__ w_c2, const float* __restrict__ b_c2,
    const float* __restrict__ b_b, const float* __restrict__ sw,
    float* __restrict__ out)
{
    // W_h1 MFMA B-fragments in LDS: entry idx = (nt*4+kk)*64 + g*16 + r, 16B each
    __shared__ f16x8 bwlds[1024];   // 16 KB

    const int tid = threadIdx.x;
    for (int e = tid; e < 1024; e += 256) {
        const int r_ = e & 15, g_ = (e >> 4) & 3, kkf = (e >> 6) & 3, ntf = e >> 8;
        const float* wr = w_h1 + (size_t)(ntf * 16 + r_) * 128 + kkf * 32 + g_ * 8;
        float4 f0 = *reinterpret_cast<const float4*>(wr);
        float4 f1 = *reinterpret_cast<const float4*>(wr + 4);
        bwlds[e] = pack8(f0, f1);
    }
    __syncthreads();

    const int lane = threadIdx.x & 63;
    const int r = lane & 15, g = lane >> 4;

    const float s0 = sw[0], s1 = sw[1], s2 = sw[2];
    const float mx = fmaxf(s0, fmaxf(s1, s2));
    const float e0 = __expf(s0 - mx), e1 = __expf(s1 - mx), e2 = __expf(s2 - mx);
    const float inv = 1.0f / (e0 + e1 + e2);
    const float W0 = e0 * inv, W1 = e1 * inv, W2 = e2 * inv;
    const float cbias = W0 * b_h2[0] + W1 * b_c2[0] + W2 * b_b[0];

    float bh1v[4], wh2v[4];
#pragma unroll
    for (int nt = 0; nt < 4; ++nt) {
        bh1v[nt] = b_h1[nt * 16 + r];
        wh2v[nt] = w_h2[nt * 16 + r] * W0;   // W0 folded
    }
    f16x8 wc2r[4];
#pragma unroll
    for (int kk = 0; kk < 4; ++kk) {
        const int k0 = kk * 32 + g * 8;
        float4 f0 = *reinterpret_cast<const float4*>(w_c2 + k0);
        float4 f1 = *reinterpret_cast<const float4*>(w_c2 + k0 + 4);
        f0.x *= W1; f0.y *= W1; f0.z *= W1; f0.w *= W1;
        f1.x *= W1; f1.y *= W1; f1.z *= W1; f1.w *= W1;
        wc2r[kk] = pack8(f0, f1);   // W1 folded
    }
    const f16x8* myb = bwlds + g * 16 + r;   // + (nt*4+kk)*64

    const int gwid = (blockIdx.x * blockDim.x + threadIdx.x) >> 6;
    const int nW = (gridDim.x * blockDim.x) >> 6;
    const int2* edge2 = reinterpret_cast<const int2*>(edge);
    const int rsel = r & 3;
    const int srcl = ((r >> 2) << 4) | r;    // shfl source lane for sc1
    const int NB = N_EDGES / 16;

    // software-pipelined edge-index fetch
    int b = gwid;
    int2 sd = make_int2(0, 0);
    if (b < NB) sd = edge2[b * 16 + r];

    for (; b < NB; b += nW) {
        const int bn = b + nW;
        int2 sdn = sd;
        if (bn < NB) sdn = edge2[bn * 16 + r];   // prefetch next iter's indices

        const int base = b * 16;
        const _Float16* ps = P + (size_t)sd.x * PROW;
        const _Float16* pd = P + (size_t)sd.y * PROW;

        // ---- issue all 20 gathers up front (2 bases, static offsets) ----
        f16x8 av[4], bv[4], yv[4], zs[4], zd[4];
#pragma unroll
        for (int kk = 0; kk < 4; ++kk) {
            const int off = kk * 32 + g * 8;
            av[kk] = *reinterpret_cast<const f16x8*>(ps + off);         // A'[src]
            bv[kk] = *reinterpret_cast<const f16x8*>(pd + 128 + off);   // B[dst]
            yv[kk] = *reinterpret_cast<const f16x8*>(pd + 256 + off);   // Y[dst]
            zs[kk] = *reinterpret_cast<const f16x8*>(ps + 384 + off);   // Zh[src]
            zd[kk] = *reinterpret_cast<const f16x8*>(pd + 384 + off);   // Zh[dst]
        }

        // ---- score1: H(16x64) = (zs .* zd) @ Wh1^T via MFMA ----
        f32x4 acc[4] = {};
#pragma unroll
        for (int kk = 0; kk < 4; ++kk) {
            f16x8 a = zs[kk] * zd[kk];
            mfma16(acc[0], a, myb[(0 * 4 + kk) * 64]);
            mfma16(acc[1], a, myb[(1 * 4 + kk) * 64]);
            mfma16(acc[2], a, myb[(2 * 4 + kk) * 64]);
            mfma16(acc[3], a, myb[(3 * 4 + kk) * 64]);
        }
        float t4[4];
#pragma unroll
        for (int rr = 0; rr < 4; ++rr) {
            float s = 0.f;
#pragma unroll
            for (int nt = 0; nt < 4; ++nt)
                s = fmaf(fmaxf(acc[nt][rr] + bh1v[nt], 0.f), wh2v[nt], s);
            t4[rr] = s;
        }
#pragma unroll
        for (int mask = 1; mask <= 8; mask <<= 1) {
#pragma unroll
            for (int rr = 0; rr < 4; ++rr)
                t4[rr] += __shfl_xor(t4[rr], mask, 16);
        }
        float u = t4[0];
        if (rsel == 1) u = t4[1];
        if (rsel == 2) u = t4[2];
        if (rsel == 3) u = t4[3];
        const float sc1w = __shfl(u, srcl, 64);  // W0-folded score1 of edge base+lane%16

        // ---- score2 & score3 on the same lane layout (edge r, slice g) ----
        float sA = 0.f, sB = 0.f;
#pragma unroll
        for (int kk = 0; kk < 4; ++kk) {
            f16x8 s = av[kk] + bv[kk];                               // v_pk_add_f16
            s = __builtin_elementwise_max(s, (f16x8)(_Float16)0.f);  // relu
#pragma unroll
            for (int j2 = 0; j2 < 4; ++j2) {
                sA = fdot2(s, wc2r[kk], j2, sA);                     // W1 pre-folded
                sB = fdot2(zs[kk], yv[kk], j2, sB);
            }
        }
        sA += __shfl_xor(sA, 16, 64);
        sA += __shfl_xor(sA, 32, 64);
        sB += __shfl_xor(sB, 16, 64);
        sB += __shfl_xor(sB, 32, 64);

        const float res = sc1w + sA + fmaf(W2, sB, cbias);
        if (lane < 16) out[base + lane] = res;
        sd = sdn;
    }
}

// ---------------- fallback: fused wave-per-edge, no workspace ----------------
__global__ __launch_bounds__(256) void fused_fallback(
    const float* __restrict__ z, const int* __restrict__ edge,
    const float* __restrict__ w_h1, const float* __restrict__ b_h1,
    const float* __restrict__ w_h2, const float* __restrict__ b_h2,
    const float* __restrict__ w_c1, const float* __restrict__ b_c1,
    const float* __restrict__ w_c2, const float* __restrict__ b_c2,
    const float* __restrict__ w_b, const float* __restrict__ b_b,
    const float* __restrict__ sw, float* __restrict__ out)
{
    __shared__ float zbuf[4][256];
    const int lane = threadIdx.x & 63;
    const int w = threadIdx.x >> 6;
    const int gw = blockIdx.x * 4 + w;
    const int nw = gridDim.x * 4;

    const float s0 = sw[0], s1 = sw[1], s2 = sw[2];
    const float mx = fmaxf(s0, fmaxf(s1, s2));
    const float e0 = __expf(s0 - mx), e1 = __expf(s1 - mx), e2 = __expf(s2 - mx);
    const float inv = 1.0f / (e0 + e1 + e2);
    const float W0 = e0 * inv, W1 = e1 * inv, W2 = e2 * inv;
    const float cbias = W0 * b_h2[0] + W1 * b_c2[0] + W2 * b_b[0];

    for (int e = gw; e < N_EDGES; e += nw) {
        const int src = edge[2 * e], dst = edge[2 * e + 1];
        const float zs0 = z[(size_t)src * 128 + lane];
        const float zs1 = z[(size_t)src * 128 + 64 + lane];
        const float zd0 = z[(size_t)dst * 128 + lane];
        const float zd1 = z[(size_t)dst * 128 + 64 + lane];
        zbuf[w][lane] = zs0; zbuf[w][64 + lane] = zs1;
        zbuf[w][128 + lane] = zd0; zbuf[w][192 + lane] = zd1;
        asm volatile("s_waitcnt lgkmcnt(0)" ::: "memory");

        float h = 0.f;
        const float* whr = w_h1 + (size_t)lane * 128;
        for (int d = 0; d < 128; ++d)
            h = fmaf(zbuf[w][d] * zbuf[w][128 + d], whr[d], h);
        float sc1 = fmaxf(h + b_h1[lane], 0.f) * w_h2[lane];

        float c0 = 0.f, c1 = 0.f;
        const float* w0r = w_c1 + (size_t)lane * 256;
        const float* w1r = w_c1 + (size_t)(lane + 64) * 256;
        for (int d = 0; d < 256; ++d) {
            const float cat = zbuf[w][d];
            c0 = fmaf(cat, w0r[d], c0);
            c1 = fmaf(cat, w1r[d], c1);
        }
        float sc2 = fmaxf(c0 + b_c1[lane], 0.f) * w_c2[lane]
                  + fmaxf(c1 + b_c1[lane + 64], 0.f) * w_c2[lane + 64];

        float t0 = 0.f, t1 = 0.f;
        const float* wb0 = w_b + (size_t)lane * 128;
        const float* wb1 = w_b + (size_t)(lane + 64) * 128;
        for (int f = 0; f < 128; ++f) {
            const float zdf = zbuf[w][128 + f];
            t0 = fmaf(wb0[f], zdf, t0);
            t1 = fmaf(wb1[f], zdf, t1);
        }
        float sc3 = zs0 * t0 + zs1 * t1;

        float v = fmaf(W0, sc1, fmaf(W1, sc2, W2 * sc3));
#pragma unroll
        for (int m = 1; m < 64; m <<= 1) v += __shfl_xor(v, m, 64);
        if (lane == 0) out[e] = v + cbias;
    }
}

extern "C" void kernel_launch(void* const* d_in, const int* in_sizes, int n_in,
                              void* d_out, int out_size, void* d_ws, size_t ws_size,
                              hipStream_t stream)
{
    const float* z    = (const float*)d_in[0];
    const int*   edge = (const int*)d_in[1];
    const float* w_h1 = (const float*)d_in[2];
    const float* b_h1 = (const float*)d_in[3];
    const float* w_h2 = (const float*)d_in[4];
    const float* b_h2 = (const float*)d_in[5];
    const float* w_c1 = (const float*)d_in[6];
    const float* b_c1 = (const float*)d_in[7];
    const float* w_c2 = (const float*)d_in[8];
    const float* b_c2 = (const float*)d_in[9];
    const float* w_b  = (const float*)d_in[10];
    const float* b_b  = (const float*)d_in[11];
    const float* sw   = (const float*)d_in[12];
    float* outp = (float*)d_out;

    const size_t needP = (size_t)N_NODES * PROW * sizeof(_Float16);  // 102.4 MB
    if (ws_size >= needP) {
        _Float16* P = (_Float16*)d_ws;
        hipLaunchKernelGGL(precomp_kernel, dim3(2048), dim3(256), 0, stream,
                           z, w_c1, b_c1, w_b, P);
        // VGPR=84 -> 6 waves/SIMD -> 6 blocks/CU co-resident; 256 CU * 6 = 1536
        hipLaunchKernelGGL(edge_kernel, dim3(1536), dim3(256), 0, stream,
                           edge, P, w_h1, b_h1, w_h2, b_h2, w_c2, b_c2, b_b, sw, outp);
    } else {
        hipLaunchKernelGGL(fused_fallback, dim3(4096), dim3(256), 0, stream,
                           z, edge, w_h1, b_h1, w_h2, b_h2, w_c1, b_c1,
                           w_c2, b_c2, w_b, b_b, sw, outp);
    }
}